// Round 1
// 14011.845 us; speedup vs baseline: 1.1880x; 1.1880x over previous
//
#include <hip/hip_runtime.h>

typedef _Float16 f16;
typedef f16 f16x2 __attribute__((ext_vector_type(2)));
typedef f16 f16x8 __attribute__((ext_vector_type(8)));
typedef float f32x4 __attribute__((ext_vector_type(4)));

#define TT 1024
#define BB 32
#define DD 1024
#define RR 256

// Packed f16 weights, interleaved so a wave's load of chunk i is one
// contiguous 1KB burst: chunk index = i*1024 + tid, 8 f16 per chunk.
// VPI chunk (i,tid): V[r=tid>>2][256*(tid&3) + 8*((i+(tid&3))&31) .. +8]
//   (the (i+s2)&31 rotation de-conflicts the matching h2 LDS reads)
// UPI chunk (i,tid): U[tid][8i .. 8i+8]
__device__ __align__(16) f16 g_VPI[RR * DD];
__device__ __align__(16) f16 g_UPI[DD * RR];

__device__ __forceinline__ float dot2f(f16x2 a, f16x2 b, float c) {
#if __has_builtin(__builtin_amdgcn_fdot2)
    return __builtin_amdgcn_fdot2(a, b, c, false);
#else
    return c + (float)a[0] * (float)b[0] + (float)a[1] * (float)b[1];
#endif
}

__device__ __forceinline__ float sigm_f(float x) { return 1.0f / (1.0f + __expf(-x)); }
__device__ __forceinline__ float tanh_f(float x) { return 1.0f - 2.0f / (1.0f + __expf(2.0f * x)); }

// ---------------------------------------------------------------------------
// Kernel 1: fused pre-GEMM (unchanged).  ax = x@Wa^T + ba ; wx = x@Wx^T + b
// ---------------------------------------------------------------------------
__global__ __launch_bounds__(256)
void fused_pregemm(const float* __restrict__ X, const float* __restrict__ Wa,
                   const float* __restrict__ Wx, const float* __restrict__ ba,
                   const float* __restrict__ bb, f16* __restrict__ axo,
                   f16* __restrict__ wxo)
{
    __shared__ __align__(16) f16 lA[64][40];
    __shared__ __align__(16) f16 lB[64][40];
    __shared__ __align__(16) f16 lC[64][40];

    const int tid = threadIdx.x;
    const int w   = tid >> 6;
    const int l   = tid & 63;
    const int la  = l & 15;
    const int qd  = l >> 4;
    const int m0  = blockIdx.x * 64;
    const int n0  = blockIdx.y * 64;
    const int sr  = tid >> 2;
    const int sk  = (tid & 3) * 8;

    f32x4 accA[4] = {};
    f32x4 accX[4] = {};

    for (int k0 = 0; k0 < DD; k0 += 32) {
        {
            const float* pX = X + (size_t)(m0 + sr) * DD + k0 + sk;
            float4 v0 = *(const float4*)pX;
            float4 v1 = *(const float4*)(pX + 4);
            f16x8 x8 = {(f16)v0.x, (f16)v0.y, (f16)v0.z, (f16)v0.w,
                        (f16)v1.x, (f16)v1.y, (f16)v1.z, (f16)v1.w};
            *(f16x8*)&lA[sr][sk] = x8;

            const float* pA = Wa + (size_t)(n0 + sr) * DD + k0 + sk;
            v0 = *(const float4*)pA;
            v1 = *(const float4*)(pA + 4);
            f16x8 a8 = {(f16)v0.x, (f16)v0.y, (f16)v0.z, (f16)v0.w,
                        (f16)v1.x, (f16)v1.y, (f16)v1.z, (f16)v1.w};
            *(f16x8*)&lB[sr][sk] = a8;

            const float* pW = Wx + (size_t)(n0 + sr) * DD + k0 + sk;
            v0 = *(const float4*)pW;
            v1 = *(const float4*)(pW + 4);
            f16x8 w8 = {(f16)v0.x, (f16)v0.y, (f16)v0.z, (f16)v0.w,
                        (f16)v1.x, (f16)v1.y, (f16)v1.z, (f16)v1.w};
            *(f16x8*)&lC[sr][sk] = w8;
        }
        __syncthreads();

        f16x8 af = *(const f16x8*)&lA[16 * w + la][qd * 8];
        #pragma unroll
        for (int c = 0; c < 4; c++) {
            f16x8 b1 = *(const f16x8*)&lB[16 * c + la][qd * 8];
            f16x8 b2 = *(const f16x8*)&lC[16 * c + la][qd * 8];
            accA[c] = __builtin_amdgcn_mfma_f32_16x16x32_f16(af, b1, accA[c], 0, 0, 0);
            accX[c] = __builtin_amdgcn_mfma_f32_16x16x32_f16(af, b2, accX[c], 0, 0, 0);
        }
        __syncthreads();
    }

    #pragma unroll
    for (int c = 0; c < 4; c++) {
        const int n = n0 + 16 * c + la;
        const float bav = ba[n];
        const float bbv = bb[n];
        #pragma unroll
        for (int r = 0; r < 4; r++) {
            const int m = m0 + 16 * w + qd * 4 + r;
            axo[(size_t)m * DD + n] = (f16)(accA[c][r] + bav);
            wxo[(size_t)m * DD + n] = (f16)(accX[c][r] + bbv);
        }
    }
}

// ---------------------------------------------------------------------------
// Kernel 1b: one-time f32 -> f16 weight pack into interleaved layouts.
// 32 blocks (= chunk index i), 1024 threads (= scan tid).
// ---------------------------------------------------------------------------
__global__ __launch_bounds__(1024)
void pack_weights(const float* __restrict__ V, const float* __restrict__ U)
{
    const int i   = blockIdx.x;     // chunk 0..31
    const int tid = threadIdx.x;    // 0..1023
    const int r   = tid >> 2;
    const int s2  = tid & 3;
    const int j   = (i + s2) & 31;

    const float* sv = V + (size_t)r * DD + 256 * s2 + 8 * j;
    f16x8 v8;
    #pragma unroll
    for (int k = 0; k < 8; k++) v8[k] = (f16)sv[k];
    ((f16x8*)g_VPI)[i * 1024 + tid] = v8;

    const float* su = U + (size_t)tid * RR + 8 * i;
    f16x8 u8;
    #pragma unroll
    for (int k = 0; k < 8; k++) u8[k] = (f16)su[k];
    ((f16x8*)g_UPI)[i * 1024 + tid] = u8;
}

// ---------------------------------------------------------------------------
// Kernel 2: sequential scan, restructured.
//   - weights streamed f16 from L2 each step (pre-packed, coalesced 1KB/wave)
//   - stage 1: thread (q2=tid>>2, s2=tid&3) owns r=q2, d-slice [256*s2, +256)
//              -> 128 dot2, reduced over s2 by two shfl_xor (no LDS, no barrier)
//   - stage 2: thread tid owns full row u[tid] over all 256 r (no partials)
//   - h f32 in register; f16 copy in LDS for the matvec
//   - 2 barriers per step (was 4), zero partial-reduction LDS arrays
// ---------------------------------------------------------------------------
__global__ __launch_bounds__(1024, 4)
void rnn_scan(const f16* __restrict__ ax, const f16* __restrict__ wx,
              const float* __restrict__ h0, float* __restrict__ out,
              float* __restrict__ hout)
{
    const int b   = blockIdx.x;
    const int tid = threadIdx.x;
    const int s2  = tid & 3;
    const int q2  = tid >> 2;

    __shared__ __align__(16) f16 h2[DD];   // h as f16 (matvec input)
    __shared__ __align__(16) f16 pl[RR];   // p as f16

    const f16x8* vp  = (const f16x8*)g_VPI + tid;  // chunk i at vp[i*1024]
    const f16x8* up  = (const f16x8*)g_UPI + tid;
    const f16x8* hch = (const f16x8*)h2;
    const f16x8* pch = (const f16x8*)pl;

    const float h0v = h0[(size_t)b * DD + tid];
    float hreg = h0v;
    h2[tid] = (f16)h0v;
    hout[(size_t)b * DD + tid] = h0v;

    const f16* axp   = ax  + (size_t)b * DD + tid;
    const f16* wxp   = wx  + (size_t)b * DD + tid;
    float*     outp  = out + (size_t)b * DD + tid;
    float*     houtp = hout + (size_t)BB * DD + (size_t)b * DD + tid;

    __syncthreads();

    #pragma unroll 1
    for (int t = 0; t < TT; t++) {
        // prefetch this step's gate inputs (HBM latency hides under stage 1/2)
        const float axv = (float)*axp;
        const float wxv = (float)*wxp;

        // ---- stage 1: p[q2] partial over my d-slice
        float a0 = 0.f, a1 = 0.f, a2 = 0.f, a3 = 0.f;
        #pragma unroll
        for (int i = 0; i < 32; i++) {
            f16x8 w  = vp[(size_t)i << 10];
            f16x8 hv = hch[32 * s2 + ((i + s2) & 31)];  // bank-rotated broadcast
            f16x2 w0 = {w[0],  w[1]},  w1 = {w[2],  w[3]};
            f16x2 w2 = {w[4],  w[5]},  w3 = {w[6],  w[7]};
            f16x2 p0 = {hv[0], hv[1]}, p1 = {hv[2], hv[3]};
            f16x2 p2 = {hv[4], hv[5]}, p3 = {hv[6], hv[7]};
            a0 = dot2f(w0, p0, a0);
            a1 = dot2f(w1, p1, a1);
            a2 = dot2f(w2, p2, a2);
            a3 = dot2f(w3, p3, a3);
        }
        float p = (a0 + a1) + (a2 + a3);
        p += __shfl_xor(p, 1);
        p += __shfl_xor(p, 2);
        if (s2 == 0) pl[q2] = (f16)p;
        __syncthreads();

        // ---- stage 2: u[tid] over all 256 r (pl reads are wave-uniform)
        float u0 = 0.f, u1 = 0.f, u2 = 0.f, u3 = 0.f;
        #pragma unroll
        for (int i = 0; i < 32; i++) {
            f16x8 w  = up[(size_t)i << 10];
            f16x8 pv = pch[i];
            f16x2 w0 = {w[0],  w[1]},  w1 = {w[2],  w[3]};
            f16x2 w2 = {w[4],  w[5]},  w3 = {w[6],  w[7]};
            f16x2 q0 = {pv[0], pv[1]}, q1 = {pv[2], pv[3]};
            f16x2 q2v = {pv[4], pv[5]}, q3 = {pv[6], pv[7]};
            u0 = dot2f(w0, q0, u0);
            u1 = dot2f(w1, q1, u1);
            u2 = dot2f(w2, q2v, u2);
            u3 = dot2f(w3, q3, u3);
        }

        // ---- elementwise
        const float uu = (u0 + u1) + (u2 + u3) + wxv;
        const float vv = tanh_f(uu);
        const float aa = sigm_f(axv);
        const float hn = aa * hreg + (1.0f - aa) * vv;
        const float so = hn * hn * sigm_f(hn);   // h * silu(h)
        *outp  = so;
        *houtp = hn;
        hreg = hn;
        h2[tid] = (f16)hn;                       // safe: h2 not read after barrier A
        axp += BB * DD; wxp += BB * DD; outp += BB * DD; houtp += BB * DD;
        __syncthreads();                         // h2/pl consumers done before next step
    }
}

extern "C" void kernel_launch(void* const* d_in, const int* in_sizes, int n_in,
                              void* d_out, int out_size, void* d_ws, size_t ws_size,
                              hipStream_t stream) {
    (void)in_sizes; (void)n_in; (void)out_size; (void)ws_size;
    const float* x  = (const float*)d_in[0];
    const float* h0 = (const float*)d_in[1];
    const float* Wa = (const float*)d_in[2];
    const float* ba = (const float*)d_in[3];
    const float* U  = (const float*)d_in[4];
    const float* V  = (const float*)d_in[5];
    const float* Wx = (const float*)d_in[6];
    const float* bb = (const float*)d_in[7];

    float* out  = (float*)d_out;                    // output [T,B,D]
    float* hout = out + (size_t)TT * BB * DD;       // h [T+1,B,D]

    f16* ax16 = (f16*)d_ws;                         // 64 MiB
    f16* wx16 = ax16 + (size_t)TT * BB * DD;        // 64 MiB

    pack_weights<<<dim3(32), dim3(1024), 0, stream>>>(V, U);
    dim3 g1(512, 16);
    fused_pregemm<<<g1, dim3(256), 0, stream>>>(x, Wa, Wx, ba, bb, ax16, wx16);
    rnn_scan<<<dim3(BB), dim3(1024), 0, stream>>>(ax16, wx16, h0, out, hout);
}